// Round 2
// baseline (172.057 us; speedup 1.0000x reference)
//
#include <hip/hip_runtime.h>

#define N_BOND   100000
#define D_DIM    192
#define N_ETYPES 36
#define E_PER_TYPE 30000
#define BATCH    256
#define TOTAL_E  (N_ETYPES * E_PER_TYPE)
#define ACC_N    (N_ETYPES * BATCH)
#define EPT      8                       // edges per thread; E_PER_TYPE % 8 == 0
#define EDGE_THREADS (TOTAL_E / EPT)     // 135000
#define EDGE_BLOCKS  ((EDGE_THREADS + 255) / 256)  // 528

// Kernel 1: hv[n] = dot(h[n, :], W).
// Quarter-wave (16 lanes) per row, 3x float4 per lane -> all 64 lanes load.
// First blocks also zero acc AND the done-counter (index ACC_N), which removes
// the separate memset dispatch; stream order guarantees visibility to kernel 2.
__global__ void hv_kernel(const float* __restrict__ h, const float* __restrict__ W,
                          float* __restrict__ hv, float* __restrict__ acc) {
    int gid = blockIdx.x * blockDim.x + threadIdx.x;
    if (gid <= ACC_N) acc[gid] = 0.f;   // acc[0..ACC_N-1] = 0, acc[ACC_N] = done counter = 0

    int wave = gid >> 6;
    int lane = threadIdx.x & 63;
    int row  = wave * 4 + (lane >> 4); // 4 rows per wave
    int ql   = lane & 15;
    if (row >= N_BOND) return;

    const float4* hp = (const float4*)(h + (size_t)row * D_DIM);
    const float4* wp = (const float4*)W;
    float v = 0.f;
#pragma unroll
    for (int k = 0; k < 3; ++k) {
        float4 a = hp[ql + 16 * k];    // 16 lanes x 16B = 256B contiguous per step
        float4 w = wp[ql + 16 * k];    // 768B total, L1-resident
        v += a.x * w.x + a.y * w.y + a.z * w.z + a.w * w.w;
    }
#pragma unroll
    for (int d = 8; d > 0; d >>= 1) v += __shfl_down(v, d, 64);
    if (ql == 0) hv[row] = v;
}

// Kernel 2: segment-sum over edges (8 edges/thread) + fused last-block softmax.
// key = t*BATCH + seg is globally non-decreasing (t grows with flat index, seg
// sorted within type). A thread's 8 edges never straddle a type (30000 % 8 == 0).
// Step 1: serial segmented fold of the 8 edges (avg segment ~117 edges, so
//         intra-thread boundaries are rare; finished partials flush via atomic).
// Step 2: 64-lane segmented inclusive scan over trailing partials; last lane of
//         each key-run flushes. ~2 atomics/wave + ~9K boundary atomics total.
// Tail:   device-scope done-counter; the LAST block to finish (guaranteed still
//         resident) runs the 256-graph softmax reading acc with agent-scope
//         atomic loads (cross-XCD coherence, G16).
__global__ void edge_softmax_kernel(const int* __restrict__ edge_src,
                                    const int* __restrict__ edge_seg,
                                    const float* __restrict__ hv,
                                    float* __restrict__ acc,
                                    int* __restrict__ done,
                                    const void* __restrict__ mask,
                                    float* __restrict__ out) {
    int tid  = blockIdx.x * blockDim.x + threadIdx.x;
    int lane = threadIdx.x & 63;
    int e0   = tid * EPT;
    bool valid = (e0 < TOTAL_E);
    int ec = valid ? e0 : (TOTAL_E - EPT);  // clamp: invalid lanes join last segment with val=0
    int t  = ec / E_PER_TYPE;

    const int4* sp = (const int4*)(edge_seg + ec);  // ec % 8 == 0 -> 32B aligned
    const int4* rp = (const int4*)(edge_src + ec);
    int4 sa = sp[0], sb = sp[1];
    int4 ra = rp[0], rb = rp[1];

    float v[EPT];
    v[0] = valid ? hv[ra.x] : 0.f;
    v[1] = valid ? hv[ra.y] : 0.f;
    v[2] = valid ? hv[ra.z] : 0.f;
    v[3] = valid ? hv[ra.w] : 0.f;
    v[4] = valid ? hv[rb.x] : 0.f;
    v[5] = valid ? hv[rb.y] : 0.f;
    v[6] = valid ? hv[rb.z] : 0.f;
    v[7] = valid ? hv[rb.w] : 0.f;

    int base = t * BATCH;
    int k[EPT] = { base + sa.x, base + sa.y, base + sa.z, base + sa.w,
                   base + sb.x, base + sb.y, base + sb.z, base + sb.w };

    int   ck = k[0];
    float cv = v[0];
#pragma unroll
    for (int i = 1; i < EPT; ++i) {
        if (k[i] == ck) cv += v[i];
        else { atomicAdd(&acc[ck], cv); ck = k[i]; cv = v[i]; }
    }

    // segmented inclusive scan over trailing partials (keys sorted across lanes)
#pragma unroll
    for (int d = 1; d < 64; d <<= 1) {
        float uv = __shfl_up(cv, d, 64);
        int   uk = __shfl_up(ck, d, 64);
        if (lane >= d && uk == ck) cv += uv;
    }
    int nk = __shfl_down(ck, 1, 64);
    if (lane == 63 || nk != ck) atomicAdd(&acc[ck], cv);

    // ---- fused softmax tail: last block to retire does the epilogue ----
    __threadfence();          // make this thread's atomics device-visible
    __syncthreads();          // whole block done + fenced
    __shared__ int is_last;
    if (threadIdx.x == 0) {
        int prev = __hip_atomic_fetch_add(done, 1, __ATOMIC_ACQ_REL,
                                          __HIP_MEMORY_SCOPE_AGENT);
        is_last = (prev == (int)gridDim.x - 1);
    }
    __syncthreads();
    if (!is_last) return;

    int b = threadIdx.x;  // 256 threads, graph b

    // Detect mask storage width: bool(1B) vs int32(4B). For int32 storage every
    // word is exactly 0 or 1; for packed 0/1 bytes a word >1 appears with
    // overwhelming probability within 16 words.
    const unsigned int* mi = (const unsigned int*)mask;
    bool is_u8 = false;
#pragma unroll
    for (int i = 0; i < 16; ++i) is_u8 |= (mi[i] > 1u);
    const unsigned char* m8  = (const unsigned char*)mask;
    const int*           m32 = (const int*)mask;

    float vv[N_ETYPES];
    float mx = -1e30f;
#pragma unroll
    for (int tt = 0; tt < N_ETYPES; ++tt) {
        float x = __hip_atomic_load(&acc[tt * BATCH + b], __ATOMIC_RELAXED,
                                    __HIP_MEMORY_SCOPE_AGENT);  // coalesced, cache-bypassing
        bool masked = is_u8 ? (m8[b * N_ETYPES + tt] != 0)
                            : (m32[b * N_ETYPES + tt] != 0);
        x = masked ? -1e9f : x;
        vv[tt] = x;
        mx = fmaxf(mx, x);
    }
    float s = 0.f;
#pragma unroll
    for (int tt = 0; tt < N_ETYPES; ++tt) { vv[tt] = expf(vv[tt] - mx); s += vv[tt]; }
    float inv = 1.f / s;
#pragma unroll
    for (int tt = 0; tt < N_ETYPES; ++tt) out[b * N_ETYPES + tt] = vv[tt] * inv;
}

extern "C" void kernel_launch(void* const* d_in, const int* in_sizes, int n_in,
                              void* d_out, int out_size, void* d_ws, size_t ws_size,
                              hipStream_t stream) {
    const float* h        = (const float*)d_in[0];   // [100000, 192]
    const float* W        = (const float*)d_in[1];   // [192, 1]
    const int*   edge_src = (const int*)d_in[2];     // [36, 30000]
    const int*   edge_seg = (const int*)d_in[3];     // [36, 30000]
    const void*  mask     = d_in[4];                 // [256, 36] bool (width auto-detected)
    float*       out      = (float*)d_out;           // [256, 36]

    float* hv   = (float*)d_ws;                      // 100000 floats
    float* acc  = (float*)((char*)d_ws + 400128);    // 9216 floats + 1 counter, 128B-aligned
    int*   done = (int*)(acc + ACC_N);

    // 100000 rows, 4 rows/wave, 4 waves/block -> 16 rows per 256-thread block
    hipLaunchKernelGGL(hv_kernel, dim3(N_BOND / 16), dim3(256), 0, stream, h, W, hv, acc);

    // 8 edges per thread; softmax fused into the last-retiring block
    hipLaunchKernelGGL(edge_softmax_kernel, dim3(EDGE_BLOCKS), dim3(256), 0, stream,
                       edge_src, edge_seg, hv, acc, done, mask, out);
}

// Round 3
// 143.719 us; speedup vs baseline: 1.1972x; 1.1972x over previous
//
#include <hip/hip_runtime.h>

#define N_BOND   100000
#define D_DIM    192
#define N_ETYPES 36
#define E_PER_TYPE 30000
#define BATCH    256
#define TOTAL_E  (N_ETYPES * E_PER_TYPE)
#define ACC_N    (N_ETYPES * BATCH)
#define EPT      4                                  // edges per thread (R1-proven)
#define EDGE_BLOCKS ((TOTAL_E / EPT + 255) / 256)   // 1055

// Kernel 1: hv[n] = dot(h[n, :], W).
// Quarter-wave (16 lanes) per row, 3x float4 per lane -> all 64 lanes load.
// First blocks also zero acc AND the done-counter (index ACC_N), removing the
// separate memset dispatch; stream order guarantees visibility to kernel 2.
__global__ void hv_kernel(const float* __restrict__ h, const float* __restrict__ W,
                          float* __restrict__ hv, float* __restrict__ acc) {
    int gid = blockIdx.x * blockDim.x + threadIdx.x;
    if (gid <= ACC_N) acc[gid] = 0.f;   // acc[0..ACC_N-1] = 0, acc[ACC_N] = done counter

    int wave = gid >> 6;
    int lane = threadIdx.x & 63;
    int row  = wave * 4 + (lane >> 4); // 4 rows per wave
    int ql   = lane & 15;
    if (row >= N_BOND) return;

    const float4* hp = (const float4*)(h + (size_t)row * D_DIM);
    const float4* wp = (const float4*)W;
    float v = 0.f;
#pragma unroll
    for (int k = 0; k < 3; ++k) {
        float4 a = hp[ql + 16 * k];    // 16 lanes x 16B = 256B contiguous per step
        float4 w = wp[ql + 16 * k];    // 768B total, L1-resident
        v += a.x * w.x + a.y * w.y + a.z * w.z + a.w * w.w;
    }
#pragma unroll
    for (int d = 8; d > 0; d >>= 1) v += __shfl_down(v, d, 64);
    if (ql == 0) hv[row] = v;
}

// Kernel 2: segment-sum over edges (4 edges/thread, R1-proven body) + fused
// last-block softmax with FENCE-FREE ordering:
//   - __syncthreads() drains vmcnt(0) per wave (compiler emits full waitcnt
//     before s_barrier), so all of this block's acc atomics have COMPLETED
//     (device-scope atomics execute at the coherent point -> globally visible).
//   - done-counter bump is a RELAXED agent-scope RMW: no buffer_wbl2/inv cache
//     maintenance (R2's 63us regression was exactly that maintenance, 528x).
//   - the last block (guaranteed still resident) reads acc with relaxed
//     agent-scope atomic loads (bypass L1) and runs the 256-graph softmax.
__global__ void edge_softmax_kernel(const int* __restrict__ edge_src,
                                    const int* __restrict__ edge_seg,
                                    const float* __restrict__ hv,
                                    float* __restrict__ acc,
                                    int* __restrict__ done,
                                    const void* __restrict__ mask,
                                    float* __restrict__ out) {
    int tid  = blockIdx.x * blockDim.x + threadIdx.x;
    int lane = threadIdx.x & 63;
    int e0   = tid * EPT;
    bool valid = (e0 < TOTAL_E);
    int ec = valid ? e0 : (TOTAL_E - EPT);  // clamp: invalid lanes join last segment with val=0
    int t  = ec / E_PER_TYPE;

    int4 s4 = ((const int4*)edge_seg)[ec >> 2];
    int4 r4 = ((const int4*)edge_src)[ec >> 2];
    float v0 = valid ? hv[r4.x] : 0.f;
    float v1 = valid ? hv[r4.y] : 0.f;
    float v2 = valid ? hv[r4.z] : 0.f;
    float v3 = valid ? hv[r4.w] : 0.f;

    int base = t * BATCH;
    int k0 = base + s4.x, k1 = base + s4.y, k2 = base + s4.z, k3 = base + s4.w;

    int   ck = k0;
    float cv = v0;
    if (k1 == ck) cv += v1; else { atomicAdd(&acc[ck], cv); ck = k1; cv = v1; }
    if (k2 == ck) cv += v2; else { atomicAdd(&acc[ck], cv); ck = k2; cv = v2; }
    if (k3 == ck) cv += v3; else { atomicAdd(&acc[ck], cv); ck = k3; cv = v3; }

    // segmented inclusive scan over trailing partials (keys sorted across lanes)
#pragma unroll
    for (int d = 1; d < 64; d <<= 1) {
        float uv = __shfl_up(cv, d, 64);
        int   uk = __shfl_up(ck, d, 64);
        if (lane >= d && uk == ck) cv += uv;
    }
    int nk = __shfl_down(ck, 1, 64);
    if (lane == 63 || nk != ck) atomicAdd(&acc[ck], cv);

    // ---- fused softmax tail: last block to retire does the epilogue ----
    __syncthreads();          // drains vmcnt(0): this block's atomics completed
    __shared__ int is_last;
    if (threadIdx.x == 0) {
        int prev = __hip_atomic_fetch_add(done, 1, __ATOMIC_RELAXED,
                                          __HIP_MEMORY_SCOPE_AGENT);
        is_last = (prev == (int)gridDim.x - 1);
    }
    __syncthreads();
    if (!is_last) return;

    int b = threadIdx.x;  // 256 threads, graph b

    // Detect mask storage width: bool(1B) vs int32(4B). For int32 storage every
    // word is exactly 0 or 1; for packed 0/1 bytes a word >1 appears with
    // overwhelming probability within 16 words.
    const unsigned int* mi = (const unsigned int*)mask;
    bool is_u8 = false;
#pragma unroll
    for (int i = 0; i < 16; ++i) is_u8 |= (mi[i] > 1u);
    const unsigned char* m8  = (const unsigned char*)mask;
    const int*           m32 = (const int*)mask;

    float vv[N_ETYPES];
    float mx = -1e30f;
#pragma unroll
    for (int tt = 0; tt < N_ETYPES; ++tt) {
        float x = __hip_atomic_load(&acc[tt * BATCH + b], __ATOMIC_RELAXED,
                                    __HIP_MEMORY_SCOPE_AGENT);  // coalesced, bypasses L1
        bool masked = is_u8 ? (m8[b * N_ETYPES + tt] != 0)
                            : (m32[b * N_ETYPES + tt] != 0);
        x = masked ? -1e9f : x;
        vv[tt] = x;
        mx = fmaxf(mx, x);
    }
    float s = 0.f;
#pragma unroll
    for (int tt = 0; tt < N_ETYPES; ++tt) { vv[tt] = expf(vv[tt] - mx); s += vv[tt]; }
    float inv = 1.f / s;
#pragma unroll
    for (int tt = 0; tt < N_ETYPES; ++tt) out[b * N_ETYPES + tt] = vv[tt] * inv;
}

extern "C" void kernel_launch(void* const* d_in, const int* in_sizes, int n_in,
                              void* d_out, int out_size, void* d_ws, size_t ws_size,
                              hipStream_t stream) {
    const float* h        = (const float*)d_in[0];   // [100000, 192]
    const float* W        = (const float*)d_in[1];   // [192, 1]
    const int*   edge_src = (const int*)d_in[2];     // [36, 30000]
    const int*   edge_seg = (const int*)d_in[3];     // [36, 30000]
    const void*  mask     = d_in[4];                 // [256, 36] bool (width auto-detected)
    float*       out      = (float*)d_out;           // [256, 36]

    float* hv   = (float*)d_ws;                      // 100000 floats
    float* acc  = (float*)((char*)d_ws + 400128);    // 9216 floats + done counter
    int*   done = (int*)(acc + ACC_N);

    // 100000 rows, 4 rows/wave, 4 waves/block -> 16 rows per 256-thread block
    hipLaunchKernelGGL(hv_kernel, dim3(N_BOND / 16), dim3(256), 0, stream, h, W, hv, acc);

    // 4 edges per thread; softmax fused into the last-retiring block (fence-free)
    hipLaunchKernelGGL(edge_softmax_kernel, dim3(EDGE_BLOCKS), dim3(256), 0, stream,
                       edge_src, edge_seg, hv, acc, done, mask, out);
}

// Round 4
// 130.022 us; speedup vs baseline: 1.3233x; 1.1053x over previous
//
#include <hip/hip_runtime.h>

#define N_BOND   100000
#define D_DIM    192
#define N_ETYPES 36
#define E_PER_TYPE 30000
#define BATCH    256
#define TOTAL_E  (N_ETYPES * E_PER_TYPE)
#define ACC_N    (N_ETYPES * BATCH)
#define EPT      2                                  // edges per thread: 8440 waves = 8.2/SIMD for latency hiding
#define EDGE_BLOCKS ((TOTAL_E / EPT + 255) / 256)   // 2110

// Kernel 1: hv[n] = dot(h[n, :], W).
// Quarter-wave (16 lanes) per row, 3x float4 per lane -> all 64 lanes load.
// First blocks also zero acc, removing the separate memset dispatch; stream
// order guarantees visibility to kernel 2. At 25000 waves this runs at the
// 76.8MB HBM read floor (~13us).
__global__ void hv_kernel(const float* __restrict__ h, const float* __restrict__ W,
                          float* __restrict__ hv, float* __restrict__ acc) {
    int gid = blockIdx.x * blockDim.x + threadIdx.x;
    if (gid < ACC_N) acc[gid] = 0.f;

    int wave = gid >> 6;
    int lane = threadIdx.x & 63;
    int row  = wave * 4 + (lane >> 4); // 4 rows per wave
    int ql   = lane & 15;
    if (row >= N_BOND) return;

    const float4* hp = (const float4*)(h + (size_t)row * D_DIM);
    const float4* wp = (const float4*)W;
    float v = 0.f;
#pragma unroll
    for (int k = 0; k < 3; ++k) {
        float4 a = hp[ql + 16 * k];    // 16 lanes x 16B = 256B contiguous per step
        float4 w = wp[ql + 16 * k];    // 768B total, L1-resident
        v += a.x * w.x + a.y * w.y + a.z * w.z + a.w * w.w;
    }
#pragma unroll
    for (int d = 8; d > 0; d >>= 1) v += __shfl_down(v, d, 64);
    if (ql == 0) hv[row] = v;
}

// Kernel 2: segment-sum over edges, 2 edges/thread.
// key = t*BATCH + seg is globally non-decreasing (t grows with flat index, seg
// sorted within type); a thread's pair never straddles a type (30000 % 2 == 0).
// Serial fold of the pair, then 64-lane segmented inclusive scan over trailing
// partials; last lane of each key-run flushes (~2 atomics/wave + ~9K boundary
// atomics over 9216 addresses -> negligible contention).
// NO block-done counter / fence: R2 showed per-block __threadfence costs ~30us
// (L2 writeback x528) and R3 showed even a relaxed single-address RMW costs
// ~13ns x gridDim ~= 13us. Separate softmax dispatch is cheaper than both.
__global__ void edge_kernel(const int* __restrict__ edge_src,
                            const int* __restrict__ edge_seg,
                            const float* __restrict__ hv,
                            float* __restrict__ acc) {
    int tid  = blockIdx.x * blockDim.x + threadIdx.x;
    int lane = threadIdx.x & 63;
    int e0   = tid * EPT;
    bool valid = (e0 < TOTAL_E);
    int ec = valid ? e0 : (TOTAL_E - EPT);  // clamp: invalid lanes join last segment with val=0
    int t  = ec / E_PER_TYPE;

    int2 s2 = ((const int2*)edge_seg)[ec >> 1];   // 64 lanes x 8B = 512B coalesced
    int2 r2 = ((const int2*)edge_src)[ec >> 1];
    float v0 = valid ? hv[r2.x] : 0.f;            // random 4B gathers, 400KB table (L2-resident)
    float v1 = valid ? hv[r2.y] : 0.f;

    int base = t * BATCH;
    int k0 = base + s2.x, k1 = base + s2.y;

    int   ck = k0;
    float cv = v0;
    if (k1 == ck) cv += v1; else { atomicAdd(&acc[ck], cv); ck = k1; cv = v1; }

    // segmented inclusive scan over trailing partials (keys sorted across lanes)
#pragma unroll
    for (int d = 1; d < 64; d <<= 1) {
        float uv = __shfl_up(cv, d, 64);
        int   uk = __shfl_up(ck, d, 64);
        if (lane >= d && uk == ck) cv += uv;
    }
    int nk = __shfl_down(ck, 1, 64);
    if (lane == 63 || nk != ck) atomicAdd(&acc[ck], cv);
}

// Kernel 3: mask + softmax over the 36 types for each of 256 graphs.
// Thread b handles graph b; acc reads are coalesced (acc[t*BATCH + b]).
__global__ void softmax_kernel(const float* __restrict__ acc,
                               const void* __restrict__ mask,
                               float* __restrict__ out) {
    int b = threadIdx.x;  // 256 threads, 1 block

    // Detect mask storage width: bool(1B) vs int32(4B). For int32 storage every
    // word is exactly 0 or 1; for packed 0/1 bytes a word >1 appears with
    // overwhelming probability within 16 words.
    const unsigned int* mi = (const unsigned int*)mask;
    bool is_u8 = false;
#pragma unroll
    for (int i = 0; i < 16; ++i) is_u8 |= (mi[i] > 1u);
    const unsigned char* m8  = (const unsigned char*)mask;
    const int*           m32 = (const int*)mask;

    float v[N_ETYPES];
    float mx = -1e30f;
#pragma unroll
    for (int t = 0; t < N_ETYPES; ++t) {
        float x = acc[t * BATCH + b];
        bool masked = is_u8 ? (m8[b * N_ETYPES + t] != 0)
                            : (m32[b * N_ETYPES + t] != 0);
        x = masked ? -1e9f : x;
        v[t] = x;
        mx = fmaxf(mx, x);
    }
    float s = 0.f;
#pragma unroll
    for (int t = 0; t < N_ETYPES; ++t) { v[t] = expf(v[t] - mx); s += v[t]; }
    float inv = 1.f / s;
#pragma unroll
    for (int t = 0; t < N_ETYPES; ++t) out[b * N_ETYPES + t] = v[t] * inv;
}

extern "C" void kernel_launch(void* const* d_in, const int* in_sizes, int n_in,
                              void* d_out, int out_size, void* d_ws, size_t ws_size,
                              hipStream_t stream) {
    const float* h        = (const float*)d_in[0];   // [100000, 192]
    const float* W        = (const float*)d_in[1];   // [192, 1]
    const int*   edge_src = (const int*)d_in[2];     // [36, 30000]
    const int*   edge_seg = (const int*)d_in[3];     // [36, 30000]
    const void*  mask     = d_in[4];                 // [256, 36] bool (width auto-detected)
    float*       out      = (float*)d_out;           // [256, 36]

    float* hv  = (float*)d_ws;                       // 100000 floats
    float* acc = (float*)((char*)d_ws + 400128);     // 9216 floats, 128B-aligned

    // 100000 rows, 4 rows/wave, 4 waves/block -> 16 rows per 256-thread block
    hipLaunchKernelGGL(hv_kernel, dim3(N_BOND / 16), dim3(256), 0, stream, h, W, hv, acc);

    // 2 edges per thread
    hipLaunchKernelGGL(edge_kernel, dim3(EDGE_BLOCKS), dim3(256), 0, stream,
                       edge_src, edge_seg, hv, acc);

    hipLaunchKernelGGL(softmax_kernel, dim3(1), dim3(256), 0, stream, acc, mask, out);
}